// Round 2
// baseline (187.953 us; speedup 1.0000x reference)
//
#include <hip/hip_runtime.h>
#include <hip/hip_bf16.h>

using bf16 = __hip_bfloat16;
typedef __attribute__((ext_vector_type(8))) short short8;
typedef __attribute__((ext_vector_type(4))) float f32x4;

__device__ __forceinline__ float bflo(unsigned u) { return __uint_as_float(u << 16); }
__device__ __forceinline__ float bfhi(unsigned u) { return __uint_as_float(u & 0xffff0000u); }
__device__ __forceinline__ unsigned short f2bf(float f) {
    union { float f; unsigned u; } v{f};
    unsigned r = v.u + 0x7fffu + ((v.u >> 16) & 1u);   // RNE (finite values only)
    return (unsigned short)(r >> 16);
}

// ---------------- weight transpose + cast: in f32[R][Cc] -> out bf16[Cc][R] ----------------
__global__ __launch_bounds__(256) void ktranspose(const float* __restrict__ in,
                                                  bf16* __restrict__ out, int R, int Cc) {
    __shared__ float t[32][33];
    int tx = threadIdx.x, ty = threadIdx.y;            // (32, 8)
    int c0 = blockIdx.x * 32, r0 = blockIdx.y * 32;
#pragma unroll
    for (int i = 0; i < 4; ++i)
        t[ty + i * 8][tx] = in[(size_t)(r0 + ty + i * 8) * Cc + c0 + tx];
    __syncthreads();
#pragma unroll
    for (int i = 0; i < 4; ++i)
        out[(size_t)(c0 + ty + i * 8) * R + r0 + tx] = __float2bfloat16(t[tx][ty + i * 8]);
}

// ------- x + interp(pos) (f32) -> bf16:  xp[m][c] = x[m][c] + 0.5*(pos[8n+3][c]+pos[8n+4][c]) ---
__global__ __launch_bounds__(256) void kaddpos(const float* __restrict__ x,
                                               const float* __restrict__ pos,
                                               bf16* __restrict__ xp) {
    size_t idx4 = (size_t)blockIdx.x * 256 + threadIdx.x;  // 4,194,304 total
    size_t e = idx4 * 4;
    int c = (int)(e & 511);
    size_t m = e >> 9;
    int n = (int)(m & 4095);
    float4 xv = *(const float4*)(x + e);
    float4 p3 = *(const float4*)(pos + (size_t)(n * 8 + 3) * 512 + c);
    float4 p4 = *(const float4*)(pos + (size_t)(n * 8 + 4) * 512 + c);
    unsigned r[2];
    float v0 = xv.x + 0.5f * (p3.x + p4.x);
    float v1 = xv.y + 0.5f * (p3.y + p4.y);
    float v2 = xv.z + 0.5f * (p3.z + p4.z);
    float v3 = xv.w + 0.5f * (p3.w + p4.w);
    r[0] = (unsigned)f2bf(v0) | ((unsigned)f2bf(v1) << 16);
    r[1] = (unsigned)f2bf(v2) | ((unsigned)f2bf(v3) << 16);
    *(uint2*)(xp + e) = *(uint2*)r;
}

// ---------------- GEMM: C[M][N] = A[M][K] @ Bt[N][K]^T + bias, bf16 in, f32 acc ----------
// 128x128 tile, BK=32, 4 waves in 2x2, each wave 4x4 fragments of 16x16x32 MFMA.
template <typename OutT>
__global__ __launch_bounds__(256) void kgemm_bt(const bf16* __restrict__ A,
                                                const bf16* __restrict__ Bt,
                                                const float* __restrict__ bias,
                                                OutT* __restrict__ C,
                                                int M, int N, int K) {
    constexpr int BM = 128, BN = 128, BK = 32, LDA = BK + 8;  // +8 pad: bank-conflict fix
    __shared__ bf16 As[BM * LDA];
    __shared__ bf16 Bs[BN * LDA];
    int tid = threadIdx.x;
    int lane = tid & 63, wave = tid >> 6;
    int wr = wave >> 1, wc = wave & 1;
    int ntn = N / BN;
    int bm = (blockIdx.x / ntn) * BM;
    int bn = (blockIdx.x % ntn) * BN;

    // staging: 512 chunks of 16B per tile; thread handles chunks tid and tid+256
    const int c0 = tid, c1 = tid + 256;
    const int r0 = c0 >> 2, ko0 = (c0 & 3) * 8;
    const int r1 = c1 >> 2, ko1 = (c1 & 3) * 8;

    f32x4 acc[4][4];
#pragma unroll
    for (int i = 0; i < 4; ++i)
#pragma unroll
        for (int j = 0; j < 4; ++j) acc[i][j] = f32x4{0.f, 0.f, 0.f, 0.f};

    const int fr = lane & 15;
    const int fk = (lane >> 4) * 8;

    for (int k0 = 0; k0 < K; k0 += BK) {
        uint4 av0 = *(const uint4*)(A + (size_t)(bm + r0) * K + k0 + ko0);
        uint4 av1 = *(const uint4*)(A + (size_t)(bm + r1) * K + k0 + ko1);
        uint4 bv0 = *(const uint4*)(Bt + (size_t)(bn + r0) * K + k0 + ko0);
        uint4 bv1 = *(const uint4*)(Bt + (size_t)(bn + r1) * K + k0 + ko1);
        __syncthreads();  // previous iteration's reads done before overwrite
        *(uint4*)(As + r0 * LDA + ko0) = av0;
        *(uint4*)(As + r1 * LDA + ko1) = av1;
        *(uint4*)(Bs + r0 * LDA + ko0) = bv0;
        *(uint4*)(Bs + r1 * LDA + ko1) = bv1;
        __syncthreads();
        short8 af[4], bfr[4];
#pragma unroll
        for (int mi = 0; mi < 4; ++mi)
            af[mi] = *(const short8*)(As + (wr * 64 + mi * 16 + fr) * LDA + fk);
#pragma unroll
        for (int nj = 0; nj < 4; ++nj)
            bfr[nj] = *(const short8*)(Bs + (wc * 64 + nj * 16 + fr) * LDA + fk);
#pragma unroll
        for (int mi = 0; mi < 4; ++mi)
#pragma unroll
            for (int nj = 0; nj < 4; ++nj)
                acc[mi][nj] = __builtin_amdgcn_mfma_f32_16x16x32_bf16(af[mi], bfr[nj], acc[mi][nj], 0, 0, 0);
    }

#pragma unroll
    for (int mi = 0; mi < 4; ++mi) {
#pragma unroll
        for (int nj = 0; nj < 4; ++nj) {
            int col = bn + wc * 64 + nj * 16 + fr;
            int row0 = bm + wr * 64 + mi * 16 + (lane >> 4) * 4;
            float bv = bias[col];
#pragma unroll
            for (int r = 0; r < 4; ++r) {
                float val = acc[mi][nj][r] + bv;
                if constexpr (sizeof(OutT) == 2)
                    C[(size_t)(row0 + r) * N + col] = (OutT)__float2bfloat16(val);
                else
                    C[(size_t)(row0 + r) * N + col] = (OutT)val;
            }
        }
    }
}

// ---------------- 8x8 per-token head attention + scrambled write ----------------
// thread = (token, head). qkv row (bf16): q@0, k@512, v@1024 (each 8 heads x 64).
__global__ __launch_bounds__(256) void kattn(const bf16* __restrict__ qkv,
                                             bf16* __restrict__ oscr) {
    int T = blockIdx.x * 256 + threadIdx.x;
    int token = T >> 3, head = T & 7;
    int b = token >> 12, n = token & 4095;
    const bf16* row = qkv + (size_t)token * 1536;

    uint4 qp[8];
#pragma unroll
    for (int c = 0; c < 8; ++c) qp[c] = *(const uint4*)(row + head * 64 + c * 8);

    float s[8];
#pragma unroll
    for (int j = 0; j < 8; ++j) {
        float acc = 0.f;
#pragma unroll
        for (int c = 0; c < 8; ++c) {
            uint4 kp = *(const uint4*)(row + 512 + j * 64 + c * 8);
            const unsigned* ku = &kp.x; const unsigned* qu = &qp[c].x;
#pragma unroll
            for (int w = 0; w < 4; ++w) {
                acc = fmaf(bflo(qu[w]), bflo(ku[w]), acc);
                acc = fmaf(bfhi(qu[w]), bfhi(ku[w]), acc);
            }
        }
        s[j] = acc * 0.125f;  // 1/sqrt(64)
    }
    float mx = s[0];
#pragma unroll
    for (int j = 1; j < 8; ++j) mx = fmaxf(mx, s[j]);
    float sum = 0.f;
#pragma unroll
    for (int j = 0; j < 8; ++j) { s[j] = __expf(s[j] - mx); sum += s[j]; }
    float inv = 1.f / sum;
#pragma unroll
    for (int j = 0; j < 8; ++j) s[j] *= inv;

    float o[64];
#pragma unroll
    for (int d = 0; d < 64; ++d) o[d] = 0.f;
#pragma unroll
    for (int j = 0; j < 8; ++j) {
        float pj = s[j];
#pragma unroll
        for (int c = 0; c < 8; ++c) {
            uint4 vp = *(const uint4*)(row + 1024 + j * 64 + c * 8);
            const unsigned* vu = &vp.x;
#pragma unroll
            for (int w = 0; w < 4; ++w) {
                o[c * 8 + w * 2]     = fmaf(pj, bflo(vu[w]), o[c * 8 + w * 2]);
                o[c * 8 + w * 2 + 1] = fmaf(pj, bfhi(vu[w]), o[c * 8 + w * 2 + 1]);
            }
        }
    }
    // scrambled layout: oscr[b*4096 + head*512 + n/8][(n%8)*64 + d]
    size_t orow = (size_t)b * 4096 + head * 512 + (n >> 3);
    bf16* op = oscr + orow * 512 + (n & 7) * 64;
#pragma unroll
    for (int c = 0; c < 8; ++c) {
        unsigned rr[4];
#pragma unroll
        for (int w = 0; w < 4; ++w)
            rr[w] = (unsigned)f2bf(o[c * 8 + w * 2]) | ((unsigned)f2bf(o[c * 8 + w * 2 + 1]) << 16);
        *(uint4*)(op + c * 8) = *(uint4*)rr;
    }
}

extern "C" void kernel_launch(void* const* d_in, const int* in_sizes, int n_in,
                              void* d_out, int out_size, void* d_ws, size_t ws_size,
                              hipStream_t stream) {
    const float* x      = (const float*)d_in[0];
    const float* pos32  = (const float*)d_in[1];
    const float* w_qkv  = (const float*)d_in[2];
    const float* b_qkv  = (const float*)d_in[3];
    const float* w_proj = (const float*)d_in[4];
    const float* b_proj = (const float*)d_in[5];
    // d_in[6] = resolution (int32) = 16 => target_len == N => interp 32768->4096 + pos-add.

    char* ws = (char*)d_ws;
    bf16* xp   = (bf16*)(ws);                  //  32768*512  bf16 = 33,554,432 B
    bf16* qkv  = (bf16*)(ws + 33554432);       //  32768*1536 bf16 = 100,663,296 B
    bf16* wqT  = (bf16*)(ws + 134217728);      //  1536*512   bf16 = 1,572,864 B
    bf16* wpT  = (bf16*)(ws + 135790592);      //  512*512    bf16 = 524,288 B
    bf16* ascr = xp;  // alias: xp is dead after the qkv GEMM

    ktranspose<<<dim3(48, 16), dim3(32, 8), 0, stream>>>(w_qkv, wqT, 512, 1536);
    ktranspose<<<dim3(16, 16), dim3(32, 8), 0, stream>>>(w_proj, wpT, 512, 512);
    kaddpos<<<16384, 256, 0, stream>>>(x, pos32, xp);
    kgemm_bt<bf16><<<256 * 12, 256, 0, stream>>>(xp, wqT, b_qkv, qkv, 32768, 1536, 512);
    kattn<<<1024, 256, 0, stream>>>(qkv, ascr);
    kgemm_bt<float><<<256 * 4, 256, 0, stream>>>(ascr, wpT, b_proj, (float*)d_out, 32768, 512, 512);
}

// Round 3
// 159.175 us; speedup vs baseline: 1.1808x; 1.1808x over previous
//
#include <hip/hip_runtime.h>
#include <hip/hip_bf16.h>

using bf16 = __hip_bfloat16;
typedef __attribute__((ext_vector_type(8))) short short8;
typedef __attribute__((ext_vector_type(4))) float f32x4;

#define AS1U(p) ((const __attribute__((address_space(1))) unsigned int*)(p))
#define AS3U(p) ((__attribute__((address_space(3))) unsigned int*)(p))

__device__ __forceinline__ float bflo(unsigned u) { return __uint_as_float(u << 16); }
__device__ __forceinline__ float bfhi(unsigned u) { return __uint_as_float(u & 0xffff0000u); }
__device__ __forceinline__ unsigned short f2bf(float f) {
    union { float f; unsigned u; } v{f};
    unsigned r = v.u + 0x7fffu + ((v.u >> 16) & 1u);   // RNE (finite values only)
    return (unsigned short)(r >> 16);
}

// ---------------- fused prep: both weight transposes (f32->bf16) + pos-interp-add ----------------
// blocks [0,768): w_qkv transpose; [768,1024): w_proj transpose; [1024,17408): addpos.
__global__ __launch_bounds__(256) void kprep(const float* __restrict__ wq,
                                             const float* __restrict__ wp,
                                             const float* __restrict__ x,
                                             const float* __restrict__ pos,
                                             bf16* __restrict__ wqT,
                                             bf16* __restrict__ wpT,
                                             bf16* __restrict__ xp) {
    int bid = blockIdx.x;
    __shared__ float t[32][33];
    if (bid < 1024) {
        const float* in; bf16* out; int Cc, bx, by;
        if (bid < 768) { in = wq; out = wqT; Cc = 1536; bx = bid % 48; by = bid / 48; }
        else { int i = bid - 768; in = wp; out = wpT; Cc = 512; bx = i & 15; by = i >> 4; }
        const int R = 512;
        int tx = threadIdx.x & 31, ty = threadIdx.x >> 5;
        int c0 = bx * 32, r0 = by * 32;
#pragma unroll
        for (int i = 0; i < 4; ++i)
            t[ty + i * 8][tx] = in[(size_t)(r0 + ty + i * 8) * Cc + c0 + tx];
        __syncthreads();
#pragma unroll
        for (int i = 0; i < 4; ++i)
            out[(size_t)(c0 + ty + i * 8) * R + r0 + tx] = __float2bfloat16(t[tx][ty + i * 8]);
    } else {
        size_t idx4 = (size_t)(bid - 1024) * 256 + threadIdx.x;  // 4,194,304 total
        size_t e = idx4 * 4;
        int c = (int)(e & 511);
        size_t m = e >> 9;
        int n = (int)(m & 4095);
        float4 xv = *(const float4*)(x + e);
        float4 p3 = *(const float4*)(pos + (size_t)(n * 8 + 3) * 512 + c);
        float4 p4 = *(const float4*)(pos + (size_t)(n * 8 + 4) * 512 + c);
        unsigned r[2];
        float v0 = xv.x + 0.5f * (p3.x + p4.x);
        float v1 = xv.y + 0.5f * (p3.y + p4.y);
        float v2 = xv.z + 0.5f * (p3.z + p4.z);
        float v3 = xv.w + 0.5f * (p3.w + p4.w);
        r[0] = (unsigned)f2bf(v0) | ((unsigned)f2bf(v1) << 16);
        r[1] = (unsigned)f2bf(v2) | ((unsigned)f2bf(v3) << 16);
        *(uint2*)(xp + e) = *(uint2*)r;
    }
}

// ------ GEMM (m97 structure): C[M][N] = A @ Bt^T + bias; bf16 in, f32 acc, OutT out ------
// 128x128 tile, BK=32, global_load_lds width-16 staging into LINEAR LDS, 4 waves 2x2,
// 4x4 fragments of v_mfma_f32_16x16x32_bf16. XCD-aware bijective block swizzle (grid%8==0).
template <typename OutT>
__global__ __launch_bounds__(256) void kgemm_lds(const bf16* __restrict__ A,
                                                 const bf16* __restrict__ Bt,
                                                 const float* __restrict__ bias,
                                                 OutT* __restrict__ C,
                                                 int M, int N, int K) {
    constexpr int BM = 128, BN = 128, BK = 32;
    __shared__ bf16 As[BM * BK];   // 8 KB, linear: byte(chunk ci)=ci*16, ci: row=ci>>2, col=(ci&3)*8
    __shared__ bf16 Bs[BN * BK];
    const int tid = threadIdx.x;
    const int lane = tid & 63, wave = tid >> 6;
    const int wr = wave >> 1, wc = wave & 1;
    const int ntn = N / 128;
    const int nwg = gridDim.x;
    const int bid = blockIdx.x;
    const int swz = (bid & 7) * (nwg >> 3) + (bid >> 3);  // XCD-contiguous tile chunks
    const int bm = (swz / ntn) * BM;
    const int bn = (swz % ntn) * BN;

    // staging: wave w, call j in {0,1} covers chunks (2w+j)*64 + lane -> LDS base (2w+j)*1024 B
    const int c0 = wave * 128 + lane;        // j=0 chunk
    const int c1 = c0 + 64;                  // j=1 chunk
    const int r0 = c0 >> 2, o0 = (c0 & 3) * 8;
    const int r1 = c1 >> 2, o1 = (c1 & 3) * 8;
    char* ldsA0 = (char*)As + wave * 2048;
    char* ldsB0 = (char*)Bs + wave * 2048;

    const bf16* a0 = A + (size_t)(bm + r0) * K + o0;
    const bf16* a1 = A + (size_t)(bm + r1) * K + o1;
    const bf16* b0 = Bt + (size_t)(bn + r0) * K + o0;
    const bf16* b1 = Bt + (size_t)(bn + r1) * K + o1;

    f32x4 acc[4][4];
#pragma unroll
    for (int i = 0; i < 4; ++i)
#pragma unroll
        for (int j = 0; j < 4; ++j) acc[i][j] = f32x4{0.f, 0.f, 0.f, 0.f};

    const int fr = lane & 15;
    const int fk = (lane >> 4) * 8;
    const bf16* arow = As + (wr * 64 + fr) * BK + fk;
    const bf16* brow = Bs + (wc * 64 + fr) * BK + fk;

    for (int k0 = 0; k0 < K; k0 += BK) {
        if (k0) __syncthreads();  // all waves done reading LDS (lgkmcnt drained at barrier)
        __builtin_amdgcn_global_load_lds(AS1U(a0 + k0), AS3U(ldsA0), 16, 0, 0);
        __builtin_amdgcn_global_load_lds(AS1U(a1 + k0), AS3U(ldsA0 + 1024), 16, 0, 0);
        __builtin_amdgcn_global_load_lds(AS1U(b0 + k0), AS3U(ldsB0), 16, 0, 0);
        __builtin_amdgcn_global_load_lds(AS1U(b1 + k0), AS3U(ldsB0 + 1024), 16, 0, 0);
        __syncthreads();          // vmcnt(0) drained at barrier -> tiles visible
        short8 af[4], bf_[4];
#pragma unroll
        for (int mi = 0; mi < 4; ++mi)
            af[mi] = *(const short8*)(arow + mi * 16 * BK);
#pragma unroll
        for (int nj = 0; nj < 4; ++nj)
            bf_[nj] = *(const short8*)(brow + nj * 16 * BK);
#pragma unroll
        for (int mi = 0; mi < 4; ++mi)
#pragma unroll
            for (int nj = 0; nj < 4; ++nj)
                acc[mi][nj] = __builtin_amdgcn_mfma_f32_16x16x32_bf16(af[mi], bf_[nj], acc[mi][nj], 0, 0, 0);
    }

#pragma unroll
    for (int mi = 0; mi < 4; ++mi) {
#pragma unroll
        for (int nj = 0; nj < 4; ++nj) {
            int col = bn + wc * 64 + nj * 16 + fr;
            int row0 = bm + wr * 64 + mi * 16 + (lane >> 4) * 4;
            float bv = bias[col];
#pragma unroll
            for (int r = 0; r < 4; ++r) {
                float val = acc[mi][nj][r] + bv;
                if constexpr (sizeof(OutT) == 2)
                    C[(size_t)(row0 + r) * N + col] = (OutT)__float2bfloat16(val);
                else
                    C[(size_t)(row0 + r) * N + col] = (OutT)val;
            }
        }
    }
}

// ---------------- 8x8 per-token head attention + scrambled write ----------------
// thread = (token, head). qkv row (bf16): q@0, k@512, v@1024 (each 8 heads x 64).
__global__ __launch_bounds__(256) void kattn(const bf16* __restrict__ qkv,
                                             bf16* __restrict__ oscr) {
    int T = blockIdx.x * 256 + threadIdx.x;
    int token = T >> 3, head = T & 7;
    int b = token >> 12, n = token & 4095;
    const bf16* row = qkv + (size_t)token * 1536;

    uint4 qp[8];
#pragma unroll
    for (int c = 0; c < 8; ++c) qp[c] = *(const uint4*)(row + head * 64 + c * 8);

    float s[8];
#pragma unroll
    for (int j = 0; j < 8; ++j) {
        float acc = 0.f;
#pragma unroll
        for (int c = 0; c < 8; ++c) {
            uint4 kp = *(const uint4*)(row + 512 + j * 64 + c * 8);
            const unsigned* ku = &kp.x; const unsigned* qu = &qp[c].x;
#pragma unroll
            for (int w = 0; w < 4; ++w) {
                acc = fmaf(bflo(qu[w]), bflo(ku[w]), acc);
                acc = fmaf(bfhi(qu[w]), bfhi(ku[w]), acc);
            }
        }
        s[j] = acc * 0.125f;  // 1/sqrt(64)
    }
    float mx = s[0];
#pragma unroll
    for (int j = 1; j < 8; ++j) mx = fmaxf(mx, s[j]);
    float sum = 0.f;
#pragma unroll
    for (int j = 0; j < 8; ++j) { s[j] = __expf(s[j] - mx); sum += s[j]; }
    float inv = 1.f / sum;
#pragma unroll
    for (int j = 0; j < 8; ++j) s[j] *= inv;

    float o[64];
#pragma unroll
    for (int d = 0; d < 64; ++d) o[d] = 0.f;
#pragma unroll
    for (int j = 0; j < 8; ++j) {
        float pj = s[j];
#pragma unroll
        for (int c = 0; c < 8; ++c) {
            uint4 vp = *(const uint4*)(row + 1024 + j * 64 + c * 8);
            const unsigned* vu = &vp.x;
#pragma unroll
            for (int w = 0; w < 4; ++w) {
                o[c * 8 + w * 2]     = fmaf(pj, bflo(vu[w]), o[c * 8 + w * 2]);
                o[c * 8 + w * 2 + 1] = fmaf(pj, bfhi(vu[w]), o[c * 8 + w * 2 + 1]);
            }
        }
    }
    // scrambled layout: oscr[b*4096 + head*512 + n/8][(n%8)*64 + d]
    size_t orow = (size_t)b * 4096 + head * 512 + (n >> 3);
    bf16* op = oscr + orow * 512 + (n & 7) * 64;
#pragma unroll
    for (int c = 0; c < 8; ++c) {
        unsigned rr[4];
#pragma unroll
        for (int w = 0; w < 4; ++w)
            rr[w] = (unsigned)f2bf(o[c * 8 + w * 2]) | ((unsigned)f2bf(o[c * 8 + w * 2 + 1]) << 16);
        *(uint4*)(op + c * 8) = *(uint4*)rr;
    }
}

extern "C" void kernel_launch(void* const* d_in, const int* in_sizes, int n_in,
                              void* d_out, int out_size, void* d_ws, size_t ws_size,
                              hipStream_t stream) {
    const float* x      = (const float*)d_in[0];
    const float* pos32  = (const float*)d_in[1];
    const float* w_qkv  = (const float*)d_in[2];
    const float* b_qkv  = (const float*)d_in[3];
    const float* w_proj = (const float*)d_in[4];
    const float* b_proj = (const float*)d_in[5];
    // d_in[6] = resolution (int32) = 16 => target_len == N => interp 32768->4096 + pos-add.

    char* ws = (char*)d_ws;
    bf16* xp   = (bf16*)(ws);                  //  32768*512  bf16 = 33,554,432 B
    bf16* qkv  = (bf16*)(ws + 33554432);       //  32768*1536 bf16 = 100,663,296 B
    bf16* wqT  = (bf16*)(ws + 134217728);      //  1536*512   bf16 = 1,572,864 B
    bf16* wpT  = (bf16*)(ws + 135790592);      //  512*512    bf16 = 524,288 B
    bf16* ascr = xp;  // alias: xp is dead after the qkv GEMM

    kprep<<<17408, 256, 0, stream>>>(w_qkv, w_proj, x, pos32, wqT, wpT, xp);
    kgemm_lds<bf16><<<256 * 12, 256, 0, stream>>>(xp, wqT, b_qkv, qkv, 32768, 1536, 512);
    kattn<<<1024, 256, 0, stream>>>(qkv, ascr);
    kgemm_lds<float><<<256 * 4, 256, 0, stream>>>(ascr, wpT, b_proj, (float*)d_out, 32768, 512, 512);
}

// Round 4
// 152.772 us; speedup vs baseline: 1.2303x; 1.0419x over previous
//
#include <hip/hip_runtime.h>
#include <hip/hip_bf16.h>

using bf16 = __hip_bfloat16;
typedef __attribute__((ext_vector_type(8))) short short8;
typedef __attribute__((ext_vector_type(4))) float f32x4;

#define AS1U(p) ((const __attribute__((address_space(1))) unsigned int*)(p))
#define AS3U(p) ((__attribute__((address_space(3))) unsigned int*)(p))

__device__ __forceinline__ float bflo(unsigned u) { return __uint_as_float(u << 16); }
__device__ __forceinline__ float bfhi(unsigned u) { return __uint_as_float(u & 0xffff0000u); }
__device__ __forceinline__ unsigned short f2bf(float f) {
    union { float f; unsigned u; } v{f};
    unsigned r = v.u + 0x7fffu + ((v.u >> 16) & 1u);   // RNE (finite values only)
    return (unsigned short)(r >> 16);
}

// ---------------- fused prep: both weight transposes (f32->bf16) + pos-interp-add ----------------
__global__ __launch_bounds__(256) void kprep(const float* __restrict__ wq,
                                             const float* __restrict__ wp,
                                             const float* __restrict__ x,
                                             const float* __restrict__ pos,
                                             bf16* __restrict__ wqT,
                                             bf16* __restrict__ wpT,
                                             bf16* __restrict__ xp) {
    int bid = blockIdx.x;
    __shared__ float t[32][33];
    if (bid < 1024) {
        const float* in; bf16* out; int Cc, bx, by;
        if (bid < 768) { in = wq; out = wqT; Cc = 1536; bx = bid % 48; by = bid / 48; }
        else { int i = bid - 768; in = wp; out = wpT; Cc = 512; bx = i & 15; by = i >> 4; }
        const int R = 512;
        int tx = threadIdx.x & 31, ty = threadIdx.x >> 5;
        int c0 = bx * 32, r0 = by * 32;
#pragma unroll
        for (int i = 0; i < 4; ++i)
            t[ty + i * 8][tx] = in[(size_t)(r0 + ty + i * 8) * Cc + c0 + tx];
        __syncthreads();
#pragma unroll
        for (int i = 0; i < 4; ++i)
            out[(size_t)(c0 + ty + i * 8) * R + r0 + tx] = __float2bfloat16(t[tx][ty + i * 8]);
    } else {
        size_t idx4 = (size_t)(bid - 1024) * 256 + threadIdx.x;  // 4,194,304 total
        size_t e = idx4 * 4;
        int c = (int)(e & 511);
        size_t m = e >> 9;
        int n = (int)(m & 4095);
        float4 xv = *(const float4*)(x + e);
        float4 p3 = *(const float4*)(pos + (size_t)(n * 8 + 3) * 512 + c);
        float4 p4 = *(const float4*)(pos + (size_t)(n * 8 + 4) * 512 + c);
        unsigned r[2];
        float v0 = xv.x + 0.5f * (p3.x + p4.x);
        float v1 = xv.y + 0.5f * (p3.y + p4.y);
        float v2 = xv.z + 0.5f * (p3.z + p4.z);
        float v3 = xv.w + 0.5f * (p3.w + p4.w);
        r[0] = (unsigned)f2bf(v0) | ((unsigned)f2bf(v1) << 16);
        r[1] = (unsigned)f2bf(v2) | ((unsigned)f2bf(v3) << 16);
        *(uint2*)(xp + e) = *(uint2*)r;
    }
}

// ======== 256x256 / BK=64 deep-pipelined GEMM: C = A @ Bt^T + bias ========
// 512 thr = 8 waves (2M x 4N), per-wave 128x64 out = 8x4 frags of 16x16x32.
// LDS 128 KiB = 2 K-tile buffers x (A 32K + B 32K). T4: counted vmcnt(8),
// raw s_barrier (no drain). T2: st_16x32 XOR swizzle, both-sides
// (pre-swizzled gload source chunk + XOR'd ds_read addr). T5: setprio.
template <typename OutT>
__global__ __launch_bounds__(512, 2) void kgemm8(const bf16* __restrict__ A,
                                                 const bf16* __restrict__ Bt,
                                                 const float* __restrict__ bias,
                                                 OutT* __restrict__ C,
                                                 int M, int N, int K) {
    __shared__ __align__(16) char smem[131072];
    const int tid = threadIdx.x;
    const int lane = tid & 63, wave = tid >> 6;
    const int wm = wave >> 2, wn = wave & 3;
    const int fr = lane & 15;
    const int lo16 = (lane >> 4) * 16;
    const int lo16s = lo16 ^ (((fr >> 2) & 1) << 5);   // T2 read-side XOR folded per-thread

    const int ntn = N >> 8;
    const int nwg = gridDim.x;
    const int bid = blockIdx.x;
    const int swz = (bid & 7) * (nwg >> 3) + (bid >> 3);   // XCD swizzle (grid % 8 == 0)
    const int bm = (swz / ntn) << 8;
    const int bn = (swz % ntn) << 8;

    // ---- staging geometry: dest chunk c = jj*512 + wave*64 + lane (linear LDS);
    // source chunk pre-swizzled: c' = c ^ (((c>>5)&1)<<1)  (involution image of byte^((byte>>9&1)<<5))
    const int lp = lane ^ (((lane >> 5) & 1) << 1);
    const int r = wave * 8 + (lp >> 3);          // 0..63 (row within 64-row jj stripe)
    const int o = (lp & 7) * 8;                  // element offset within row
    const bf16* srcA[4]; const bf16* srcB[4];    // [h*2+jj]
#pragma unroll
    for (int h = 0; h < 2; ++h)
#pragma unroll
        for (int jj = 0; jj < 2; ++jj) {
            srcA[h * 2 + jj] = A  + (size_t)(bm + h * 128 + jj * 64 + r) * K + o;
            srcB[h * 2 + jj] = Bt + (size_t)(bn + h * 128 + jj * 64 + r) * K + o;
        }

    // fragment read bases (per K-tile buffer b): A half = wm, B half = wn>>1, B sub = wn&1
    const char* pAb[2]; const char* pBb[2];
#pragma unroll
    for (int b = 0; b < 2; ++b) {
        pAb[b] = smem + b * 65536 + wm * 16384 + fr * 128 + lo16s;
        pBb[b] = smem + b * 65536 + 32768 + (wn >> 1) * 16384 + (wn & 1) * 8192 + fr * 128 + lo16s;
    }

    f32x4 acc[8][4];
#pragma unroll
    for (int i = 0; i < 8; ++i)
#pragma unroll
        for (int j = 0; j < 4; ++j) acc[i][j] = f32x4{0.f, 0.f, 0.f, 0.f};

    auto stage = [&](int kt, int b) {
        char* base = smem + b * 65536;
#pragma unroll
        for (int i = 0; i < 4; ++i) {
            const int off = (i >> 1) * 16384 + (i & 1) * 8192 + wave * 1024;
            __builtin_amdgcn_global_load_lds(AS1U(srcA[i] + kt * 64), AS3U(base + off), 16, 0, 0);
            __builtin_amdgcn_global_load_lds(AS1U(srcB[i] + kt * 64), AS3U(base + 32768 + off), 16, 0, 0);
        }
    };

    stage(0, 0);
    stage(1, 1);     // 16 loads in flight

#pragma unroll
    for (int t = 0; t < 8; ++t) {
        const int b = t & 1;
        // own 8 loads for tile t complete (t+1's 8 may stay in flight); barrier makes it collective
        if (t < 7) asm volatile("s_waitcnt vmcnt(8)" ::: "memory");
        else       asm volatile("s_waitcnt vmcnt(0)" ::: "memory");
        __builtin_amdgcn_s_barrier();
        __builtin_amdgcn_sched_barrier(0);
        const char* pA = pAb[b];
        const char* pB = pBb[b];
#pragma unroll
        for (int kk = 0; kk < 2; ++kk) {
            short8 af[8];
#pragma unroll
            for (int mi = 0; mi < 8; ++mi)
                af[mi] = *(const short8*)(pA + mi * 2048 + kk * 64);
#pragma unroll
            for (int njh = 0; njh < 2; ++njh) {
                short8 bfr[2];
#pragma unroll
                for (int j = 0; j < 2; ++j)
                    bfr[j] = *(const short8*)(pB + (njh * 2 + j) * 2048 + kk * 64);
                __builtin_amdgcn_s_setprio(1);
#pragma unroll
                for (int mi = 0; mi < 8; ++mi)
#pragma unroll
                    for (int j = 0; j < 2; ++j)
                        acc[mi][njh * 2 + j] = __builtin_amdgcn_mfma_f32_16x16x32_bf16(
                            af[mi], bfr[j], acc[mi][njh * 2 + j], 0, 0, 0);
                __builtin_amdgcn_s_setprio(0);
            }
        }
        __builtin_amdgcn_sched_barrier(0);
        __builtin_amdgcn_s_barrier();          // all waves done reading buf b
        if (t < 6) stage(t + 2, b);            // safe: buf b provably dead
    }

    // ---- epilogue: bias + store (scalar; col = lane-contiguous 16-wide runs)
#pragma unroll
    for (int mi = 0; mi < 8; ++mi) {
#pragma unroll
        for (int nj = 0; nj < 4; ++nj) {
            int col = bn + wn * 64 + nj * 16 + fr;
            int row0 = bm + wm * 128 + mi * 16 + (lane >> 4) * 4;
            float bv = bias[col];
#pragma unroll
            for (int rr = 0; rr < 4; ++rr) {
                float val = acc[mi][nj][rr] + bv;
                if constexpr (sizeof(OutT) == 2)
                    C[(size_t)(row0 + rr) * N + col] = (OutT)__float2bfloat16(val);
                else
                    C[(size_t)(row0 + rr) * N + col] = (OutT)val;
            }
        }
    }
}

// ---------------- 8x8 per-token head attention + scrambled write ----------------
__global__ __launch_bounds__(256) void kattn(const bf16* __restrict__ qkv,
                                             bf16* __restrict__ oscr) {
    int T = blockIdx.x * 256 + threadIdx.x;
    int token = T >> 3, head = T & 7;
    int b = token >> 12, n = token & 4095;
    const bf16* row = qkv + (size_t)token * 1536;

    uint4 qp[8];
#pragma unroll
    for (int c = 0; c < 8; ++c) qp[c] = *(const uint4*)(row + head * 64 + c * 8);

    float s[8];
#pragma unroll
    for (int j = 0; j < 8; ++j) {
        float acc = 0.f;
#pragma unroll
        for (int c = 0; c < 8; ++c) {
            uint4 kp = *(const uint4*)(row + 512 + j * 64 + c * 8);
            const unsigned* ku = &kp.x; const unsigned* qu = &qp[c].x;
#pragma unroll
            for (int w = 0; w < 4; ++w) {
                acc = fmaf(bflo(qu[w]), bflo(ku[w]), acc);
                acc = fmaf(bfhi(qu[w]), bfhi(ku[w]), acc);
            }
        }
        s[j] = acc * 0.125f;
    }
    float mx = s[0];
#pragma unroll
    for (int j = 1; j < 8; ++j) mx = fmaxf(mx, s[j]);
    float sum = 0.f;
#pragma unroll
    for (int j = 0; j < 8; ++j) { s[j] = __expf(s[j] - mx); sum += s[j]; }
    float inv = 1.f / sum;
#pragma unroll
    for (int j = 0; j < 8; ++j) s[j] *= inv;

    float o[64];
#pragma unroll
    for (int d = 0; d < 64; ++d) o[d] = 0.f;
#pragma unroll
    for (int j = 0; j < 8; ++j) {
        float pj = s[j];
#pragma unroll
        for (int c = 0; c < 8; ++c) {
            uint4 vp = *(const uint4*)(row + 1024 + j * 64 + c * 8);
            const unsigned* vu = &vp.x;
#pragma unroll
            for (int w = 0; w < 4; ++w) {
                o[c * 8 + w * 2]     = fmaf(pj, bflo(vu[w]), o[c * 8 + w * 2]);
                o[c * 8 + w * 2 + 1] = fmaf(pj, bfhi(vu[w]), o[c * 8 + w * 2 + 1]);
            }
        }
    }
    size_t orow = (size_t)b * 4096 + head * 512 + (n >> 3);
    bf16* op = oscr + orow * 512 + (n & 7) * 64;
#pragma unroll
    for (int c = 0; c < 8; ++c) {
        unsigned rr[4];
#pragma unroll
        for (int w = 0; w < 4; ++w)
            rr[w] = (unsigned)f2bf(o[c * 8 + w * 2]) | ((unsigned)f2bf(o[c * 8 + w * 2 + 1]) << 16);
        *(uint4*)(op + c * 8) = *(uint4*)rr;
    }
}

extern "C" void kernel_launch(void* const* d_in, const int* in_sizes, int n_in,
                              void* d_out, int out_size, void* d_ws, size_t ws_size,
                              hipStream_t stream) {
    const float* x      = (const float*)d_in[0];
    const float* pos32  = (const float*)d_in[1];
    const float* w_qkv  = (const float*)d_in[2];
    const float* b_qkv  = (const float*)d_in[3];
    const float* w_proj = (const float*)d_in[4];
    const float* b_proj = (const float*)d_in[5];
    // d_in[6] = resolution = 16 => target_len == N => interp 32768->4096 + pos-add.

    char* ws = (char*)d_ws;
    bf16* xp   = (bf16*)(ws);                  //  32768*512  bf16
    bf16* qkv  = (bf16*)(ws + 33554432);       //  32768*1536 bf16
    bf16* wqT  = (bf16*)(ws + 134217728);      //  1536*512   bf16
    bf16* wpT  = (bf16*)(ws + 135790592);      //  512*512    bf16
    bf16* ascr = xp;  // alias: xp dead after qkv GEMM

    kprep<<<17408, 256, 0, stream>>>(w_qkv, w_proj, x, pos32, wqT, wpT, xp);
    kgemm8<bf16><<<768, 512, 0, stream>>>(xp, wqT, b_qkv, qkv, 32768, 1536, 512);
    kattn<<<1024, 256, 0, stream>>>(qkv, ascr);
    kgemm8<float><<<256, 512, 0, stream>>>(ascr, wpT, b_proj, (float*)d_out, 32768, 512, 512);
}

// Round 5
// 146.814 us; speedup vs baseline: 1.2802x; 1.0406x over previous
//
#include <hip/hip_runtime.h>
#include <hip/hip_bf16.h>

using bf16 = __hip_bfloat16;
typedef __attribute__((ext_vector_type(8))) short short8;
typedef __attribute__((ext_vector_type(4))) float f32x4;

#define AS1U(p) ((const __attribute__((address_space(1))) unsigned int*)(p))
#define AS3U(p) ((__attribute__((address_space(3))) unsigned int*)(p))

__device__ __forceinline__ float bflo(unsigned u) { return __uint_as_float(u << 16); }
__device__ __forceinline__ float bfhi(unsigned u) { return __uint_as_float(u & 0xffff0000u); }
__device__ __forceinline__ unsigned short f2bf(float f) {
    union { float f; unsigned u; } v{f};
    unsigned r = v.u + 0x7fffu + ((v.u >> 16) & 1u);   // RNE (finite values only)
    return (unsigned short)(r >> 16);
}

// ---------------- fused prep: both weight transposes (f32->bf16) + pos-interp-add ----------------
__global__ __launch_bounds__(256) void kprep(const float* __restrict__ wq,
                                             const float* __restrict__ wp,
                                             const float* __restrict__ x,
                                             const float* __restrict__ pos,
                                             bf16* __restrict__ wqT,
                                             bf16* __restrict__ wpT,
                                             bf16* __restrict__ xp) {
    int bid = blockIdx.x;
    __shared__ float t[32][33];
    if (bid < 1024) {
        const float* in; bf16* out; int Cc, bx, by;
        if (bid < 768) { in = wq; out = wqT; Cc = 1536; bx = bid % 48; by = bid / 48; }
        else { int i = bid - 768; in = wp; out = wpT; Cc = 512; bx = i & 15; by = i >> 4; }
        const int R = 512;
        int tx = threadIdx.x & 31, ty = threadIdx.x >> 5;
        int c0 = bx * 32, r0 = by * 32;
#pragma unroll
        for (int i = 0; i < 4; ++i)
            t[ty + i * 8][tx] = in[(size_t)(r0 + ty + i * 8) * Cc + c0 + tx];
        __syncthreads();
#pragma unroll
        for (int i = 0; i < 4; ++i)
            out[(size_t)(c0 + ty + i * 8) * R + r0 + tx] = __float2bfloat16(t[tx][ty + i * 8]);
    } else {
        size_t idx4 = (size_t)(bid - 1024) * 256 + threadIdx.x;  // 4,194,304 total
        size_t e = idx4 * 4;
        int c = (int)(e & 511);
        size_t m = e >> 9;
        int n = (int)(m & 4095);
        float4 xv = *(const float4*)(x + e);
        float4 p3 = *(const float4*)(pos + (size_t)(n * 8 + 3) * 512 + c);
        float4 p4 = *(const float4*)(pos + (size_t)(n * 8 + 4) * 512 + c);
        unsigned r[2];
        float v0 = xv.x + 0.5f * (p3.x + p4.x);
        float v1 = xv.y + 0.5f * (p3.y + p4.y);
        float v2 = xv.z + 0.5f * (p3.z + p4.z);
        float v3 = xv.w + 0.5f * (p3.w + p4.w);
        r[0] = (unsigned)f2bf(v0) | ((unsigned)f2bf(v1) << 16);
        r[1] = (unsigned)f2bf(v2) | ((unsigned)f2bf(v3) << 16);
        *(uint2*)(xp + e) = *(uint2*)r;
    }
}

// ======== 256x256 / BK=64 deep-pipelined GEMM: C = A @ Bt^T + bias ========
// 512 thr = 8 waves (2M x 4N), per-wave 128x64 out = 8x4 frags of 16x16x32.
// T2 full swizzle: LDS slot (row, c) holds global (row, c ^ (row&7)), c = 16B chunk.
//   write: gload_lds linear dest; SOURCE col chunk pre-permuted ((l&7)^((l>>3)&7)).
//   read:  byte = row*128 + ((colchunk ^ (row&7))<<4); per-thread constant XOR.
// T4: counted vmcnt(8) + raw s_barrier. T5: setprio around MFMA clusters.
template <typename OutT>
__global__ __launch_bounds__(512, 2) void kgemm8(const bf16* __restrict__ A,
                                                 const bf16* __restrict__ Bt,
                                                 const float* __restrict__ bias,
                                                 OutT* __restrict__ C,
                                                 int M, int N, int K) {
    __shared__ __align__(16) char smem[131072];
    const int tid = threadIdx.x;
    const int lane = tid & 63, wave = tid >> 6;
    const int wm = wave >> 2, wn = wave & 3;
    const int fr = lane & 15;
    const int g = lane >> 4;                       // 0..3 (colchunk for kk=0)
    const int s0 = ((g ^ (fr & 7)) << 4);          // swizzled col-byte, kk=0
    const int s1 = (((g | 4) ^ (fr & 7)) << 4);    // swizzled col-byte, kk=1

    const int ntn = N >> 8;
    const int nwg = gridDim.x;
    const int bid = blockIdx.x;
    const int swz = (bid & 7) * (nwg >> 3) + (bid >> 3);   // XCD swizzle (grid % 8 == 0)
    const int bm = (swz / ntn) << 8;
    const int bn = (swz % ntn) << 8;

    // ---- staging: lane l -> LDS chunk (linear); source col pre-swizzled
    const int r = wave * 8 + (lane >> 3);                  // row within 64-row stripe
    const int o = ((lane & 7) ^ ((lane >> 3) & 7)) * 8;    // element offset (swizzled)
    const bf16* srcA[4]; const bf16* srcB[4];              // [h*2+jj]
#pragma unroll
    for (int h = 0; h < 2; ++h)
#pragma unroll
        for (int jj = 0; jj < 2; ++jj) {
            srcA[h * 2 + jj] = A  + (size_t)(bm + h * 128 + jj * 64 + r) * K + o;
            srcB[h * 2 + jj] = Bt + (size_t)(bn + h * 128 + jj * 64 + r) * K + o;
        }

    // fragment read bases per buffer b and kk
    const char* pA0[2]; const char* pA1[2]; const char* pB0[2]; const char* pB1[2];
#pragma unroll
    for (int b = 0; b < 2; ++b) {
        const char* abase = smem + b * 65536 + wm * 16384 + fr * 128;
        const char* bbase = smem + b * 65536 + 32768 + (wn >> 1) * 16384 + (wn & 1) * 8192 + fr * 128;
        pA0[b] = abase + s0; pA1[b] = abase + s1;
        pB0[b] = bbase + s0; pB1[b] = bbase + s1;
    }

    f32x4 acc[8][4];
#pragma unroll
    for (int i = 0; i < 8; ++i)
#pragma unroll
        for (int j = 0; j < 4; ++j) acc[i][j] = f32x4{0.f, 0.f, 0.f, 0.f};

    auto stage = [&](int kt, int b) {
        char* base = smem + b * 65536;
#pragma unroll
        for (int i = 0; i < 4; ++i) {
            const int off = (i >> 1) * 16384 + (i & 1) * 8192 + wave * 1024;
            __builtin_amdgcn_global_load_lds(AS1U(srcA[i] + kt * 64), AS3U(base + off), 16, 0, 0);
            __builtin_amdgcn_global_load_lds(AS1U(srcB[i] + kt * 64), AS3U(base + 32768 + off), 16, 0, 0);
        }
    };

    stage(0, 0);
    stage(1, 1);     // 16 loads in flight

#pragma unroll
    for (int t = 0; t < 8; ++t) {
        const int b = t & 1;
        if (t < 7) asm volatile("s_waitcnt vmcnt(8)" ::: "memory");
        else       asm volatile("s_waitcnt vmcnt(0)" ::: "memory");
        __builtin_amdgcn_s_barrier();
        __builtin_amdgcn_sched_barrier(0);
#pragma unroll
        for (int kk = 0; kk < 2; ++kk) {
            const char* pA = kk ? pA1[b] : pA0[b];
            const char* pB = kk ? pB1[b] : pB0[b];
            short8 af[8];
#pragma unroll
            for (int mi = 0; mi < 8; ++mi)
                af[mi] = *(const short8*)(pA + mi * 2048);
#pragma unroll
            for (int njh = 0; njh < 2; ++njh) {
                short8 bfr[2];
#pragma unroll
                for (int j = 0; j < 2; ++j)
                    bfr[j] = *(const short8*)(pB + (njh * 2 + j) * 2048);
                __builtin_amdgcn_s_setprio(1);
#pragma unroll
                for (int mi = 0; mi < 8; ++mi)
#pragma unroll
                    for (int j = 0; j < 2; ++j)
                        acc[mi][njh * 2 + j] = __builtin_amdgcn_mfma_f32_16x16x32_bf16(
                            af[mi], bfr[j], acc[mi][njh * 2 + j], 0, 0, 0);
                __builtin_amdgcn_s_setprio(0);
            }
        }
        __builtin_amdgcn_sched_barrier(0);
        __builtin_amdgcn_s_barrier();          // all waves done reading buf b
        if (t < 6) stage(t + 2, b);            // safe: buf b provably dead
    }

    // ---- epilogue: bias + store
#pragma unroll
    for (int mi = 0; mi < 8; ++mi) {
#pragma unroll
        for (int nj = 0; nj < 4; ++nj) {
            int col = bn + wn * 64 + nj * 16 + fr;
            int row0 = bm + wm * 128 + mi * 16 + (lane >> 4) * 4;
            float bv = bias[col];
#pragma unroll
            for (int rr = 0; rr < 4; ++rr) {
                float val = acc[mi][nj][rr] + bv;
                if constexpr (sizeof(OutT) == 2)
                    C[(size_t)(row0 + rr) * N + col] = (OutT)__float2bfloat16(val);
                else
                    C[(size_t)(row0 + rr) * N + col] = (OutT)val;
            }
        }
    }
}

// ---------------- 8x8 per-token head attention + scrambled write ----------------
__global__ __launch_bounds__(256) void kattn(const bf16* __restrict__ qkv,
                                             bf16* __restrict__ oscr) {
    int T = blockIdx.x * 256 + threadIdx.x;
    int token = T >> 3, head = T & 7;
    int b = token >> 12, n = token & 4095;
    const bf16* row = qkv + (size_t)token * 1536;

    uint4 qp[8];
#pragma unroll
    for (int c = 0; c < 8; ++c) qp[c] = *(const uint4*)(row + head * 64 + c * 8);

    float s[8];
#pragma unroll
    for (int j = 0; j < 8; ++j) {
        float acc = 0.f;
#pragma unroll
        for (int c = 0; c < 8; ++c) {
            uint4 kp = *(const uint4*)(row + 512 + j * 64 + c * 8);
            const unsigned* ku = &kp.x; const unsigned* qu = &qp[c].x;
#pragma unroll
            for (int w = 0; w < 4; ++w) {
                acc = fmaf(bflo(qu[w]), bflo(ku[w]), acc);
                acc = fmaf(bfhi(qu[w]), bfhi(ku[w]), acc);
            }
        }
        s[j] = acc * 0.125f;
    }
    float mx = s[0];
#pragma unroll
    for (int j = 1; j < 8; ++j) mx = fmaxf(mx, s[j]);
    float sum = 0.f;
#pragma unroll
    for (int j = 0; j < 8; ++j) { s[j] = __expf(s[j] - mx); sum += s[j]; }
    float inv = 1.f / sum;
#pragma unroll
    for (int j = 0; j < 8; ++j) s[j] *= inv;

    float o[64];
#pragma unroll
    for (int d = 0; d < 64; ++d) o[d] = 0.f;
#pragma unroll
    for (int j = 0; j < 8; ++j) {
        float pj = s[j];
#pragma unroll
        for (int c = 0; c < 8; ++c) {
            uint4 vp = *(const uint4*)(row + 1024 + j * 64 + c * 8);
            const unsigned* vu = &vp.x;
#pragma unroll
            for (int w = 0; w < 4; ++w) {
                o[c * 8 + w * 2]     = fmaf(pj, bflo(vu[w]), o[c * 8 + w * 2]);
                o[c * 8 + w * 2 + 1] = fmaf(pj, bfhi(vu[w]), o[c * 8 + w * 2 + 1]);
            }
        }
    }
    size_t orow = (size_t)b * 4096 + head * 512 + (n >> 3);
    bf16* op = oscr + orow * 512 + (n & 7) * 64;
#pragma unroll
    for (int c = 0; c < 8; ++c) {
        unsigned rr[4];
#pragma unroll
        for (int w = 0; w < 4; ++w)
            rr[w] = (unsigned)f2bf(o[c * 8 + w * 2]) | ((unsigned)f2bf(o[c * 8 + w * 2 + 1]) << 16);
        *(uint4*)(op + c * 8) = *(uint4*)rr;
    }
}

extern "C" void kernel_launch(void* const* d_in, const int* in_sizes, int n_in,
                              void* d_out, int out_size, void* d_ws, size_t ws_size,
                              hipStream_t stream) {
    const float* x      = (const float*)d_in[0];
    const float* pos32  = (const float*)d_in[1];
    const float* w_qkv  = (const float*)d_in[2];
    const float* b_qkv  = (const float*)d_in[3];
    const float* w_proj = (const float*)d_in[4];
    const float* b_proj = (const float*)d_in[5];
    // d_in[6] = resolution = 16 => target_len == N => interp 32768->4096 + pos-add.

    char* ws = (char*)d_ws;
    bf16* xp   = (bf16*)(ws);                  //  32768*512  bf16
    bf16* qkv  = (bf16*)(ws + 33554432);       //  32768*1536 bf16
    bf16* wqT  = (bf16*)(ws + 134217728);      //  1536*512   bf16
    bf16* wpT  = (bf16*)(ws + 135790592);      //  512*512    bf16
    bf16* ascr = xp;  // alias: xp dead after qkv GEMM

    kprep<<<17408, 256, 0, stream>>>(w_qkv, w_proj, x, pos32, wqT, wpT, xp);
    kgemm8<bf16><<<768, 512, 0, stream>>>(xp, wqT, b_qkv, qkv, 32768, 1536, 512);
    kattn<<<1024, 256, 0, stream>>>(qkv, ascr);
    kgemm8<float><<<256, 512, 0, stream>>>(ascr, wpT, b_proj, (float*)d_out, 32768, 512, 512);
}

// Round 6
// 144.020 us; speedup vs baseline: 1.3050x; 1.0194x over previous
//
#include <hip/hip_runtime.h>
#include <hip/hip_bf16.h>

using bf16 = __hip_bfloat16;
typedef __attribute__((ext_vector_type(8))) short short8;
typedef __attribute__((ext_vector_type(4))) float f32x4;

#define AS1U(p) ((const __attribute__((address_space(1))) unsigned int*)(p))
#define AS3U(p) ((__attribute__((address_space(3))) unsigned int*)(p))

__device__ __forceinline__ float bflo(unsigned u) { return __uint_as_float(u << 16); }
__device__ __forceinline__ float bfhi(unsigned u) { return __uint_as_float(u & 0xffff0000u); }
__device__ __forceinline__ unsigned short f2bf(float f) {
    union { float f; unsigned u; } v{f};
    unsigned r = v.u + 0x7fffu + ((v.u >> 16) & 1u);   // RNE (finite values only)
    return (unsigned short)(r >> 16);
}

// ---------------- fused prep: both weight transposes (f32->bf16) + pos-interp-add ----------------
__global__ __launch_bounds__(256) void kprep(const float* __restrict__ wq,
                                             const float* __restrict__ wp,
                                             const float* __restrict__ x,
                                             const float* __restrict__ pos,
                                             bf16* __restrict__ wqT,
                                             bf16* __restrict__ wpT,
                                             bf16* __restrict__ xp) {
    int bid = blockIdx.x;
    __shared__ float t[32][33];
    if (bid < 1024) {
        const float* in; bf16* out; int Cc, bx, by;
        if (bid < 768) { in = wq; out = wqT; Cc = 1536; bx = bid % 48; by = bid / 48; }
        else { int i = bid - 768; in = wp; out = wpT; Cc = 512; bx = i & 15; by = i >> 4; }
        const int R = 512;
        int tx = threadIdx.x & 31, ty = threadIdx.x >> 5;
        int c0 = bx * 32, r0 = by * 32;
#pragma unroll
        for (int i = 0; i < 4; ++i)
            t[ty + i * 8][tx] = in[(size_t)(r0 + ty + i * 8) * Cc + c0 + tx];
        __syncthreads();
#pragma unroll
        for (int i = 0; i < 4; ++i)
            out[(size_t)(c0 + ty + i * 8) * R + r0 + tx] = __float2bfloat16(t[tx][ty + i * 8]);
    } else {
        size_t idx4 = (size_t)(bid - 1024) * 256 + threadIdx.x;  // 4,194,304 total
        size_t e = idx4 * 4;
        int c = (int)(e & 511);
        size_t m = e >> 9;
        int n = (int)(m & 4095);
        float4 xv = *(const float4*)(x + e);
        float4 p3 = *(const float4*)(pos + (size_t)(n * 8 + 3) * 512 + c);
        float4 p4 = *(const float4*)(pos + (size_t)(n * 8 + 4) * 512 + c);
        unsigned r[2];
        float v0 = xv.x + 0.5f * (p3.x + p4.x);
        float v1 = xv.y + 0.5f * (p3.y + p4.y);
        float v2 = xv.z + 0.5f * (p3.z + p4.z);
        float v3 = xv.w + 0.5f * (p3.w + p4.w);
        r[0] = (unsigned)f2bf(v0) | ((unsigned)f2bf(v1) << 16);
        r[1] = (unsigned)f2bf(v2) | ((unsigned)f2bf(v3) << 16);
        *(uint2*)(xp + e) = *(uint2*)r;
    }
}

// ======== 256x256 fine-phased GEMM (T3+T4+T2+T5): C = A @ Bt^T + bias ========
// 512 thr = 8 waves (2M x 4N), per-wave 128x64 out = 8x4 frags of 16x16x32.
// BK=32; LDS = 4-slot ring x (A 16KB + B 16KB). Tile t reads slot t&3; during
// tile t we stage tile t+3 into slot (t+3)&3 (prev occupant t-1 is dead).
// Per tile: 2 phases {ds_reads + stage-half | s_barrier | lgkmcnt(0) | 16 MFMA | s_barrier}.
// Boundary s_waitcnt vmcnt(8) (counted, never 0 until epilogue).
// Swizzle (64B rows, 4x 16B chunks): phys slot p = ((row&1)<<2 | chunk) ^ ((row>>1)&7);
// read side folds to a per-thread constant; stage source pre-permuted (linear gload dest).
template <typename OutT>
__global__ __launch_bounds__(512, 2) void kgemm8(const bf16* __restrict__ A,
                                                 const bf16* __restrict__ Bt,
                                                 const float* __restrict__ bias,
                                                 OutT* __restrict__ C,
                                                 int M, int N, int K_) {
    constexpr int K = 512;                       // fixed for this problem (16 K-tiles)
    __shared__ __align__(16) char smem[131072];  // 4 x (A 16384 + B 16384)
    const int tid = threadIdx.x;
    const int lane = tid & 63, wave = tid >> 6;
    const int wm = wave >> 2, wn = wave & 3;
    const int fr = lane & 15;
    const int g = lane >> 4;                     // k-chunk 0..3 (8 elems = 16B)

    // read-side swizzled per-thread bases
    const int p_rd = (((fr & 1) << 2) | g) ^ ((fr >> 1) & 7);
    const int tbA = (wm * 64 + (fr >> 1)) * 128 + p_rd * 16;   // + mi*1024
    const int tbB = (wn * 32 + (fr >> 1)) * 128 + p_rd * 16;   // + nj*1024

    const int ntn = N >> 8;
    const int nwg = gridDim.x;
    const int bid = blockIdx.x;
    const int swz = (bid & 7) * (nwg >> 3) + (bid >> 3);       // XCD swizzle (grid%8==0)
    const int bm = (swz / ntn) << 8;
    const int bn = (swz % ntn) << 8;

    // stage-side: lane l, region g2 in {0,1}: LDS dest byte (wave*2+g2)*1024 + l*16 (linear);
    // source pre-permuted: q = (l&7)^(l>>3); row = wave*32 + g2*16 + 2*(l>>3) + (q>>2); chunk = q&3.
    const int q = (lane & 7) ^ (lane >> 3);
    const int srow = wave * 32 + 2 * (lane >> 3) + ((q >> 2) & 1);
    const int scol = (q & 3) * 8;
    const bf16* sA[2]; const bf16* sB[2];
#pragma unroll
    for (int g2 = 0; g2 < 2; ++g2) {
        sA[g2] = A  + (size_t)(bm + srow + g2 * 16) * K + scol;
        sB[g2] = Bt + (size_t)(bn + srow + g2 * 16) * K + scol;
    }
    const int dA0 = wave * 2048, dA1 = wave * 2048 + 1024;

    f32x4 acc[8][4];
#pragma unroll
    for (int i = 0; i < 8; ++i)
#pragma unroll
        for (int j = 0; j < 4; ++j) acc[i][j] = f32x4{0.f, 0.f, 0.f, 0.f};

    auto stageA = [&](int kt, int slot) {
        char* d = smem + slot * 32768;
        __builtin_amdgcn_global_load_lds(AS1U(sA[0] + kt * 32), AS3U(d + dA0), 16, 0, 0);
        __builtin_amdgcn_global_load_lds(AS1U(sA[1] + kt * 32), AS3U(d + dA1), 16, 0, 0);
    };
    auto stageB = [&](int kt, int slot) {
        char* d = smem + slot * 32768 + 16384;
        __builtin_amdgcn_global_load_lds(AS1U(sB[0] + kt * 32), AS3U(d + dA0), 16, 0, 0);
        __builtin_amdgcn_global_load_lds(AS1U(sB[1] + kt * 32), AS3U(d + dA1), 16, 0, 0);
    };

    // prologue: stage tiles 0,1,2 (12 loads); tile0 landed when <=8 outstanding
    stageA(0, 0); stageB(0, 0);
    stageA(1, 1); stageB(1, 1);
    stageA(2, 2); stageB(2, 2);
    asm volatile("s_waitcnt vmcnt(8)" ::: "memory");
    __builtin_amdgcn_s_barrier();

#pragma unroll
    for (int t = 0; t < 16; ++t) {
        const int r = t & 3, rs = (t + 3) & 3;
        const char* pa = smem + r * 32768;
        const char* pb = pa + 16384;
        // ---- phase 0: reads (af 0..3 + all bfr) + stage A-half of t+3
        short8 af0[4], bfr[4], af1[4];
#pragma unroll
        for (int mi = 0; mi < 4; ++mi) af0[mi] = *(const short8*)(pa + tbA + mi * 1024);
#pragma unroll
        for (int nj = 0; nj < 4; ++nj) bfr[nj] = *(const short8*)(pb + tbB + nj * 1024);
        if (t < 13) stageA(t + 3, rs);
        __builtin_amdgcn_s_barrier();
        asm volatile("s_waitcnt lgkmcnt(0)" ::: "memory");
        __builtin_amdgcn_sched_barrier(0);
        __builtin_amdgcn_s_setprio(1);
#pragma unroll
        for (int mi = 0; mi < 4; ++mi)
#pragma unroll
            for (int nj = 0; nj < 4; ++nj)
                acc[mi][nj] = __builtin_amdgcn_mfma_f32_16x16x32_bf16(af0[mi], bfr[nj], acc[mi][nj], 0, 0, 0);
        __builtin_amdgcn_s_setprio(0);
        __builtin_amdgcn_s_barrier();
        // ---- phase 1: reads (af 4..7) + stage B-half of t+3
#pragma unroll
        for (int mi = 0; mi < 4; ++mi) af1[mi] = *(const short8*)(pa + tbA + (mi + 4) * 1024);
        if (t < 13) stageB(t + 3, rs);
        __builtin_amdgcn_s_barrier();
        asm volatile("s_waitcnt lgkmcnt(0)" ::: "memory");
        __builtin_amdgcn_sched_barrier(0);
        __builtin_amdgcn_s_setprio(1);
#pragma unroll
        for (int mi = 0; mi < 4; ++mi)
#pragma unroll
            for (int nj = 0; nj < 4; ++nj)
                acc[mi + 4][nj] = __builtin_amdgcn_mfma_f32_16x16x32_bf16(af1[mi], bfr[nj], acc[mi + 4][nj], 0, 0, 0);
        __builtin_amdgcn_s_setprio(0);
        // boundary: next tile's data must be landed; keep later prefetches in flight
        if (t <= 12)      asm volatile("s_waitcnt vmcnt(8)" ::: "memory");
        else if (t == 13) asm volatile("s_waitcnt vmcnt(4)" ::: "memory");
        else if (t == 14) asm volatile("s_waitcnt vmcnt(0)" ::: "memory");
        __builtin_amdgcn_s_barrier();
    }

    // ---- epilogue: bias + store
#pragma unroll
    for (int mi = 0; mi < 8; ++mi) {
#pragma unroll
        for (int nj = 0; nj < 4; ++nj) {
            int col = bn + wn * 64 + nj * 16 + fr;
            int row0 = bm + wm * 128 + mi * 16 + (lane >> 4) * 4;
            float bv = bias[col];
#pragma unroll
            for (int rr = 0; rr < 4; ++rr) {
                float val = acc[mi][nj][rr] + bv;
                if constexpr (sizeof(OutT) == 2)
                    C[(size_t)(row0 + rr) * N + col] = (OutT)__float2bfloat16(val);
                else
                    C[(size_t)(row0 + rr) * N + col] = (OutT)val;
            }
        }
    }
}

// ---------------- 8x8 per-token head attention + scrambled write ----------------
__global__ __launch_bounds__(256) void kattn(const bf16* __restrict__ qkv,
                                             bf16* __restrict__ oscr) {
    int T = blockIdx.x * 256 + threadIdx.x;
    int token = T >> 3, head = T & 7;
    int b = token >> 12, n = token & 4095;
    const bf16* row = qkv + (size_t)token * 1536;

    uint4 qp[8];
#pragma unroll
    for (int c = 0; c < 8; ++c) qp[c] = *(const uint4*)(row + head * 64 + c * 8);

    float s[8];
#pragma unroll
    for (int j = 0; j < 8; ++j) {
        float acc = 0.f;
#pragma unroll
        for (int c = 0; c < 8; ++c) {
            uint4 kp = *(const uint4*)(row + 512 + j * 64 + c * 8);
            const unsigned* ku = &kp.x; const unsigned* qu = &qp[c].x;
#pragma unroll
            for (int w = 0; w < 4; ++w) {
                acc = fmaf(bflo(qu[w]), bflo(ku[w]), acc);
                acc = fmaf(bfhi(qu[w]), bfhi(ku[w]), acc);
            }
        }
        s[j] = acc * 0.125f;
    }
    float mx = s[0];
#pragma unroll
    for (int j = 1; j < 8; ++j) mx = fmaxf(mx, s[j]);
    float sum = 0.f;
#pragma unroll
    for (int j = 0; j < 8; ++j) { s[j] = __expf(s[j] - mx); sum += s[j]; }
    float inv = 1.f / sum;
#pragma unroll
    for (int j = 0; j < 8; ++j) s[j] *= inv;

    float o[64];
#pragma unroll
    for (int d = 0; d < 64; ++d) o[d] = 0.f;
#pragma unroll
    for (int j = 0; j < 8; ++j) {
        float pj = s[j];
#pragma unroll
        for (int c = 0; c < 8; ++c) {
            uint4 vp = *(const uint4*)(row + 1024 + j * 64 + c * 8);
            const unsigned* vu = &vp.x;
#pragma unroll
            for (int w = 0; w < 4; ++w) {
                o[c * 8 + w * 2]     = fmaf(pj, bflo(vu[w]), o[c * 8 + w * 2]);
                o[c * 8 + w * 2 + 1] = fmaf(pj, bfhi(vu[w]), o[c * 8 + w * 2 + 1]);
            }
        }
    }
    size_t orow = (size_t)b * 4096 + head * 512 + (n >> 3);
    bf16* op = oscr + orow * 512 + (n & 7) * 64;
#pragma unroll
    for (int c = 0; c < 8; ++c) {
        unsigned rr[4];
#pragma unroll
        for (int w = 0; w < 4; ++w)
            rr[w] = (unsigned)f2bf(o[c * 8 + w * 2]) | ((unsigned)f2bf(o[c * 8 + w * 2 + 1]) << 16);
        *(uint4*)(op + c * 8) = *(uint4*)rr;
    }
}

extern "C" void kernel_launch(void* const* d_in, const int* in_sizes, int n_in,
                              void* d_out, int out_size, void* d_ws, size_t ws_size,
                              hipStream_t stream) {
    const float* x      = (const float*)d_in[0];
    const float* pos32  = (const float*)d_in[1];
    const float* w_qkv  = (const float*)d_in[2];
    const float* b_qkv  = (const float*)d_in[3];
    const float* w_proj = (const float*)d_in[4];
    const float* b_proj = (const float*)d_in[5];
    // d_in[6] = resolution = 16 => target_len == N => interp 32768->4096 + pos-add.

    char* ws = (char*)d_ws;
    bf16* xp   = (bf16*)(ws);                  //  32768*512  bf16
    bf16* qkv  = (bf16*)(ws + 33554432);       //  32768*1536 bf16
    bf16* wqT  = (bf16*)(ws + 134217728);      //  1536*512   bf16
    bf16* wpT  = (bf16*)(ws + 135790592);      //  512*512    bf16
    bf16* ascr = xp;  // alias: xp dead after qkv GEMM

    kprep<<<17408, 256, 0, stream>>>(w_qkv, w_proj, x, pos32, wqT, wpT, xp);
    kgemm8<bf16><<<768, 512, 0, stream>>>(xp, wqT, b_qkv, qkv, 32768, 1536, 512);
    kattn<<<1024, 256, 0, stream>>>(qkv, ascr);
    kgemm8<float><<<256, 512, 0, stream>>>(ascr, wpT, b_proj, (float*)d_out, 32768, 512, 512);
}

// Round 7
// 143.060 us; speedup vs baseline: 1.3138x; 1.0067x over previous
//
#include <hip/hip_runtime.h>
#include <hip/hip_bf16.h>

using bf16 = __hip_bfloat16;
typedef __attribute__((ext_vector_type(8))) short short8;
typedef __attribute__((ext_vector_type(4))) float f32x4;

#define AS1U(p) ((const __attribute__((address_space(1))) unsigned int*)(p))
#define AS3U(p) ((__attribute__((address_space(3))) unsigned int*)(p))

__device__ __forceinline__ float bflo(unsigned u) { return __uint_as_float(u << 16); }
__device__ __forceinline__ float bfhi(unsigned u) { return __uint_as_float(u & 0xffff0000u); }
__device__ __forceinline__ unsigned short f2bf(float f) {
    union { float f; unsigned u; } v{f};
    unsigned r = v.u + 0x7fffu + ((v.u >> 16) & 1u);   // RNE (finite values only)
    return (unsigned short)(r >> 16);
}

// ---------------- fused prep: both weight transposes (f32->bf16) + pos-interp-add ----------------
__global__ __launch_bounds__(256) void kprep(const float* __restrict__ wq,
                                             const float* __restrict__ wp,
                                             const float* __restrict__ x,
                                             const float* __restrict__ pos,
                                             bf16* __restrict__ wqT,
                                             bf16* __restrict__ wpT,
                                             bf16* __restrict__ xp) {
    int bid = blockIdx.x;
    __shared__ float t[32][33];
    if (bid < 1024) {
        const float* in; bf16* out; int Cc, bx, by;
        if (bid < 768) { in = wq; out = wqT; Cc = 1536; bx = bid % 48; by = bid / 48; }
        else { int i = bid - 768; in = wp; out = wpT; Cc = 512; bx = i & 15; by = i >> 4; }
        const int R = 512;
        int tx = threadIdx.x & 31, ty = threadIdx.x >> 5;
        int c0 = bx * 32, r0 = by * 32;
#pragma unroll
        for (int i = 0; i < 4; ++i)
            t[ty + i * 8][tx] = in[(size_t)(r0 + ty + i * 8) * Cc + c0 + tx];
        __syncthreads();
#pragma unroll
        for (int i = 0; i < 4; ++i)
            out[(size_t)(c0 + ty + i * 8) * R + r0 + tx] = __float2bfloat16(t[tx][ty + i * 8]);
    } else {
        size_t idx4 = (size_t)(bid - 1024) * 256 + threadIdx.x;  // 4,194,304 total
        size_t e = idx4 * 4;
        int c = (int)(e & 511);
        size_t m = e >> 9;
        int n = (int)(m & 4095);
        float4 xv = *(const float4*)(x + e);
        float4 p3 = *(const float4*)(pos + (size_t)(n * 8 + 3) * 512 + c);
        float4 p4 = *(const float4*)(pos + (size_t)(n * 8 + 4) * 512 + c);
        unsigned r[2];
        float v0 = xv.x + 0.5f * (p3.x + p4.x);
        float v1 = xv.y + 0.5f * (p3.y + p4.y);
        float v2 = xv.z + 0.5f * (p3.z + p4.z);
        float v3 = xv.w + 0.5f * (p3.w + p4.w);
        r[0] = (unsigned)f2bf(v0) | ((unsigned)f2bf(v1) << 16);
        r[1] = (unsigned)f2bf(v2) | ((unsigned)f2bf(v3) << 16);
        *(uint2*)(xp + e) = *(uint2*)r;
    }
}

// ======== 256x256 GEMM, single compiler-scheduled region per K-tile ========
// 512 thr = 8 waves (2M x 4N), per-wave 128x64 out = 8x4 frags of 16x16x32.
// BK=32; LDS = 4-slot ring x (A 16KB + B 16KB) = 128 KiB. Tile t reads slot t&3;
// stage(t+3) into slot (t+3)&3 (prev occupant t-1 dead: >=1 barrier + lgkm drain ago).
// Per tile ONE region {stage issue, 12 ds_read_b128, 32 MFMA} - compiler inserts
// fine-grained lgkmcnt; then lgkmcnt(0) + counted vmcnt + sched_barrier(0) + ONE s_barrier.
// vmcnt audit: needed stages are always the oldest outstanding vmem, so extra
// compiler loads (bias etc.) can only over-wait, never under-wait.
// Swizzle (64B rows, 4x16B chunks): phys slot p = ((row&1)<<2 | chunk) ^ ((row>>1)&7);
// read side = per-thread constant; stage source pre-permuted (linear gload dest).
template <typename OutT>
__global__ __launch_bounds__(512, 2) void kgemm8(const bf16* __restrict__ A,
                                                 const bf16* __restrict__ Bt,
                                                 const float* __restrict__ bias,
                                                 OutT* __restrict__ C,
                                                 int M, int N, int K_) {
    constexpr int K = 512;                       // fixed for this problem (16 K-tiles)
    __shared__ __align__(16) char smem[131072];  // 4 x (A 16384 + B 16384)
    const int tid = threadIdx.x;
    const int lane = tid & 63, wave = tid >> 6;
    const int wm = wave >> 2, wn = wave & 3;
    const int fr = lane & 15;
    const int g = lane >> 4;                     // k-chunk 0..3 (8 elems = 16B)

    // read-side swizzled per-thread bases
    const int p_rd = (((fr & 1) << 2) | g) ^ ((fr >> 1) & 7);
    const int tbA = (wm * 64 + (fr >> 1)) * 128 + p_rd * 16;   // + mi*1024
    const int tbB = (wn * 32 + (fr >> 1)) * 128 + p_rd * 16;   // + nj*1024

    const int ntn = N >> 8;
    const int nwg = gridDim.x;
    const int bid = blockIdx.x;
    const int swz = (bid & 7) * (nwg >> 3) + (bid >> 3);       // XCD swizzle (grid%8==0)
    const int bm = (swz / ntn) << 8;
    const int bn = (swz % ntn) << 8;

    // stage-side: lane l, region g2 in {0,1}: LDS dest byte (wave*2+g2)*1024 + l*16 (linear);
    // source pre-permuted: q = (l&7)^(l>>3); row = wave*32 + g2*16 + 2*(l>>3) + (q>>2); chunk = q&3.
    const int q = (lane & 7) ^ (lane >> 3);
    const int srow = wave * 32 + 2 * (lane >> 3) + ((q >> 2) & 1);
    const int scol = (q & 3) * 8;
    const bf16* sA[2]; const bf16* sB[2];
#pragma unroll
    for (int g2 = 0; g2 < 2; ++g2) {
        sA[g2] = A  + (size_t)(bm + srow + g2 * 16) * K + scol;
        sB[g2] = Bt + (size_t)(bn + srow + g2 * 16) * K + scol;
    }
    const int dA0 = wave * 2048, dA1 = wave * 2048 + 1024;

    f32x4 acc[8][4];
#pragma unroll
    for (int i = 0; i < 8; ++i)
#pragma unroll
        for (int j = 0; j < 4; ++j) acc[i][j] = f32x4{0.f, 0.f, 0.f, 0.f};

    auto stageA = [&](int kt, int slot) {
        char* d = smem + slot * 32768;
        __builtin_amdgcn_global_load_lds(AS1U(sA[0] + kt * 32), AS3U(d + dA0), 16, 0, 0);
        __builtin_amdgcn_global_load_lds(AS1U(sA[1] + kt * 32), AS3U(d + dA1), 16, 0, 0);
    };
    auto stageB = [&](int kt, int slot) {
        char* d = smem + slot * 32768 + 16384;
        __builtin_amdgcn_global_load_lds(AS1U(sB[0] + kt * 32), AS3U(d + dA0), 16, 0, 0);
        __builtin_amdgcn_global_load_lds(AS1U(sB[1] + kt * 32), AS3U(d + dA1), 16, 0, 0);
    };

    // prologue: stage tiles 0,1,2 (12 loads/wave); tile0 landed when <=8 outstanding
    stageA(0, 0); stageB(0, 0);
    stageA(1, 1); stageB(1, 1);
    stageA(2, 2); stageB(2, 2);
    asm volatile("s_waitcnt vmcnt(8)" ::: "memory");
    __builtin_amdgcn_s_barrier();

#pragma unroll
    for (int t = 0; t < 16; ++t) {
        const int rd = t & 3, wrs = (t + 3) & 3;
        const char* pa = smem + rd * 32768;
        const char* pb = pa + 16384;
        if (t < 13) { stageA(t + 3, wrs); stageB(t + 3, wrs); }
        short8 af[8], bfr[4];
#pragma unroll
        for (int mi = 0; mi < 8; ++mi) af[mi] = *(const short8*)(pa + tbA + mi * 1024);
#pragma unroll
        for (int nj = 0; nj < 4; ++nj) bfr[nj] = *(const short8*)(pb + tbB + nj * 1024);
#pragma unroll
        for (int mi = 0; mi < 8; ++mi)
#pragma unroll
            for (int nj = 0; nj < 4; ++nj)
                acc[mi][nj] = __builtin_amdgcn_mfma_f32_16x16x32_bf16(af[mi], bfr[nj], acc[mi][nj], 0, 0, 0);
        // fence cluster: own ds_reads serviced; next tile's stages landed (collective after barrier)
        asm volatile("s_waitcnt lgkmcnt(0)" ::: "memory");
        if (t <= 12)      asm volatile("s_waitcnt vmcnt(8)" ::: "memory");
        else if (t == 13) asm volatile("s_waitcnt vmcnt(4)" ::: "memory");
        else if (t == 14) asm volatile("s_waitcnt vmcnt(0)" ::: "memory");
        __builtin_amdgcn_sched_barrier(0);
        __builtin_amdgcn_s_barrier();
    }

    // ---- epilogue: bias + store
#pragma unroll
    for (int mi = 0; mi < 8; ++mi) {
#pragma unroll
        for (int nj = 0; nj < 4; ++nj) {
            int col = bn + wn * 64 + nj * 16 + fr;
            int row0 = bm + wm * 128 + mi * 16 + (lane >> 4) * 4;
            float bv = bias[col];
#pragma unroll
            for (int rr = 0; rr < 4; ++rr) {
                float val = acc[mi][nj][rr] + bv;
                if constexpr (sizeof(OutT) == 2)
                    C[(size_t)(row0 + rr) * N + col] = (OutT)__float2bfloat16(val);
                else
                    C[(size_t)(row0 + rr) * N + col] = (OutT)val;
            }
        }
    }
}

// ---------------- 8x8 per-token head attention + scrambled write ----------------
__global__ __launch_bounds__(256) void kattn(const bf16* __restrict__ qkv,
                                             bf16* __restrict__ oscr) {
    int T = blockIdx.x * 256 + threadIdx.x;
    int token = T >> 3, head = T & 7;
    int b = token >> 12, n = token & 4095;
    const bf16* row = qkv + (size_t)token * 1536;

    uint4 qp[8];
#pragma unroll
    for (int c = 0; c < 8; ++c) qp[c] = *(const uint4*)(row + head * 64 + c * 8);

    float s[8];
#pragma unroll
    for (int j = 0; j < 8; ++j) {
        float acc = 0.f;
#pragma unroll
        for (int c = 0; c < 8; ++c) {
            uint4 kp = *(const uint4*)(row + 512 + j * 64 + c * 8);
            const unsigned* ku = &kp.x; const unsigned* qu = &qp[c].x;
#pragma unroll
            for (int w = 0; w < 4; ++w) {
                acc = fmaf(bflo(qu[w]), bflo(ku[w]), acc);
                acc = fmaf(bfhi(qu[w]), bfhi(ku[w]), acc);
            }
        }
        s[j] = acc * 0.125f;
    }
    float mx = s[0];
#pragma unroll
    for (int j = 1; j < 8; ++j) mx = fmaxf(mx, s[j]);
    float sum = 0.f;
#pragma unroll
    for (int j = 0; j < 8; ++j) { s[j] = __expf(s[j] - mx); sum += s[j]; }
    float inv = 1.f / sum;
#pragma unroll
    for (int j = 0; j < 8; ++j) s[j] *= inv;

    float o[64];
#pragma unroll
    for (int d = 0; d < 64; ++d) o[d] = 0.f;
#pragma unroll
    for (int j = 0; j < 8; ++j) {
        float pj = s[j];
#pragma unroll
        for (int c = 0; c < 8; ++c) {
            uint4 vp = *(const uint4*)(row + 1024 + j * 64 + c * 8);
            const unsigned* vu = &vp.x;
#pragma unroll
            for (int w = 0; w < 4; ++w) {
                o[c * 8 + w * 2]     = fmaf(pj, bflo(vu[w]), o[c * 8 + w * 2]);
                o[c * 8 + w * 2 + 1] = fmaf(pj, bfhi(vu[w]), o[c * 8 + w * 2 + 1]);
            }
        }
    }
    size_t orow = (size_t)b * 4096 + head * 512 + (n >> 3);
    bf16* op = oscr + orow * 512 + (n & 7) * 64;
#pragma unroll
    for (int c = 0; c < 8; ++c) {
        unsigned rr[4];
#pragma unroll
        for (int w = 0; w < 4; ++w)
            rr[w] = (unsigned)f2bf(o[c * 8 + w * 2]) | ((unsigned)f2bf(o[c * 8 + w * 2 + 1]) << 16);
        *(uint4*)(op + c * 8) = *(uint4*)rr;
    }
}

extern "C" void kernel_launch(void* const* d_in, const int* in_sizes, int n_in,
                              void* d_out, int out_size, void* d_ws, size_t ws_size,
                              hipStream_t stream) {
    const float* x      = (const float*)d_in[0];
    const float* pos32  = (const float*)d_in[1];
    const float* w_qkv  = (const float*)d_in[2];
    const float* b_qkv  = (const float*)d_in[3];
    const float* w_proj = (const float*)d_in[4];
    const float* b_proj = (const float*)d_in[5];
    // d_in[6] = resolution = 16 => target_len == N => interp 32768->4096 + pos-add.

    char* ws = (char*)d_ws;
    bf16* xp   = (bf16*)(ws);                  //  32768*512  bf16
    bf16* qkv  = (bf16*)(ws + 33554432);       //  32768*1536 bf16
    bf16* wqT  = (bf16*)(ws + 134217728);      //  1536*512   bf16
    bf16* wpT  = (bf16*)(ws + 135790592);      //  512*512    bf16
    bf16* ascr = xp;  // alias: xp dead after qkv GEMM

    kprep<<<17408, 256, 0, stream>>>(w_qkv, w_proj, x, pos32, wqT, wpT, xp);
    kgemm8<bf16><<<768, 512, 0, stream>>>(xp, wqT, b_qkv, qkv, 32768, 1536, 512);
    kattn<<<1024, 256, 0, stream>>>(qkv, ascr);
    kgemm8<float><<<256, 512, 0, stream>>>(ascr, wpT, b_proj, (float*)d_out, 32768, 512, 512);
}